// Round 7
// baseline (4455.599 us; speedup 1.0000x reference)
//
#include <hip/hip_runtime.h>
#include <hip/hip_bf16.h>
#include <stdint.h>

// Problem constants (fixed by setup_inputs)
constexpr int NH   = 32;            // query heads
constexpr int NKVH = 8;             // kv heads
constexpr int HD   = 128;           // head dim
constexpr int DM   = 4096;          // model dim (K of the GEMM)
constexpr int B    = 2;
constexpr int S    = 1024;
constexpr int T    = B * S;         // 2048
constexpr int QKVN = (NH + 2 * NKVH) * HD;  // 6144
constexpr int KOFF = NH * HD;               // 4096 (k section)
constexpr int VOFF = (NH + NKVH) * HD;      // 5120 (v section)

typedef float floatx4 __attribute__((ext_vector_type(4)));
typedef floatx4 floatx4_a __attribute__((may_alias));

// ---------------------------------------------------------------------------
// 1) GEMM: qkv = hidden @ w_qkv, fp32 in, fp32 out. LDS-tiled, BM=BN=64,
//    BK=16; 256 threads; 4x4 micro-tile each. (Cross-validated structure.)
// ---------------------------------------------------------------------------
__global__ __launch_bounds__(256) void gemm_naive(
    const float* __restrict__ A,   // T x DM
    const float* __restrict__ W,   // DM x QKVN
    float* __restrict__ C) {       // T x QKVN  (fp32 now)
  __shared__ float As[16][65];  // [k][m], padded
  __shared__ float Bs[16][64];  // [k][n]
  const int tid = threadIdx.x;
  const int tx = tid & 15, ty = tid >> 4;
  const int m0 = blockIdx.y * 64, n0 = blockIdx.x * 64;

  const int sm = tid >> 2, sk4 = (tid & 3) * 4;   // A staging
  const int bk = tid >> 4, bn4 = (tid & 15) * 4;  // W staging

  float acc[4][4];
#pragma unroll
  for (int i = 0; i < 4; ++i)
#pragma unroll
    for (int j = 0; j < 4; ++j) acc[i][j] = 0.f;

  for (int kk = 0; kk < DM; kk += 16) {
    __syncthreads();
    floatx4 va = *(const floatx4_a*)(A + (size_t)(m0 + sm) * DM + kk + sk4);
#pragma unroll
    for (int e = 0; e < 4; ++e) As[sk4 + e][sm] = va[e];
    floatx4 vb = *(const floatx4_a*)(W + (size_t)(kk + bk) * QKVN + n0 + bn4);
    *(floatx4*)&Bs[bk][bn4] = vb;
    __syncthreads();
#pragma unroll
    for (int k = 0; k < 16; ++k) {
      float a[4], b[4];
#pragma unroll
      for (int e = 0; e < 4; ++e) a[e] = As[k][ty * 4 + e];
#pragma unroll
      for (int e = 0; e < 4; ++e) b[e] = Bs[k][tx * 4 + e];
#pragma unroll
      for (int i = 0; i < 4; ++i)
#pragma unroll
        for (int j = 0; j < 4; ++j) acc[i][j] += a[i] * b[j];
    }
  }
#pragma unroll
  for (int i = 0; i < 4; ++i)
#pragma unroll
    for (int j = 0; j < 4; ++j)
      C[(size_t)(m0 + ty * 4 + i) * QKVN + n0 + tx * 4 + j] = acc[i][j];
}

// ---------------------------------------------------------------------------
// 2) RoPE in-place on q and k sections of qkv (fp32). cos/sin fp32 (T,128)
//    with cos[t][d] == cos[t][d+64] (emb = concat(freqs, freqs)).
//    q/k head sections are contiguous (heads 0..39), so one indexing covers
//    both; v (heads 40..47 equivalent) untouched.
// ---------------------------------------------------------------------------
__global__ __launch_bounds__(256) void rope_kernel(
    float* __restrict__ qkv, const float* __restrict__ cs,
    const float* __restrict__ sn) {
  const int idx = blockIdx.x * 256 + threadIdx.x;  // T * 40 heads * 64 pairs
  const int d = idx & 63;
  const int tmp = idx >> 6;
  const int head = tmp % (NH + NKVH);
  const int tt = tmp / (NH + NKVH);
  float* row = qkv + (size_t)tt * QKVN + head * HD;
  const float c = cs[tt * HD + d];
  const float s = sn[tt * HD + d];
  const float x1 = row[d];
  const float x2 = row[d + 64];
  row[d] = x1 * c - x2 * s;
  row[d + 64] = x2 * c + x1 * s;
}

// ---------------------------------------------------------------------------
// 3) Attention (cross-validated vs MFMA impl): one wave per (b, h, q).
//    Lane owns output dims d=lane and d=lane+64. Score via shuffle reduce;
//    streaming online softmax in fp32. fp32 in, fp32 out.
// ---------------------------------------------------------------------------
__global__ __launch_bounds__(256) void attn_naive(
    const float* __restrict__ qkv, float* __restrict__ out) {
  const int wid = (int)((blockIdx.x * 256 + threadIdx.x) >> 6);
  const int lane = threadIdx.x & 63;
  const int q = wid & (S - 1);      // S = 1024
  const int bh = wid >> 10;         // b*NH + h
  const int h = bh & (NH - 1);
  const int b = bh >> 5;
  const int kvh = h >> 2;           // n_rep = 4
  const float scale = 0.08838834764831845f;

  const float* qrow = qkv + (size_t)(b * S + q) * QKVN + h * HD;
  const float q1 = qrow[lane];
  const float q2 = qrow[lane + 64];
  const float* kb = qkv + (size_t)b * S * QKVN + KOFF + kvh * HD;
  const float* vb = qkv + (size_t)b * S * QKVN + VOFF + kvh * HD;

  float m = -__builtin_inff();
  float l = 0.f, o1 = 0.f, o2 = 0.f;
  for (int k = 0; k <= q; ++k) {
    const float* kr = kb + (size_t)k * QKVN;
    float ps = q1 * kr[lane] + q2 * kr[lane + 64];
    ps += __shfl_xor(ps, 1);
    ps += __shfl_xor(ps, 2);
    ps += __shfl_xor(ps, 4);
    ps += __shfl_xor(ps, 8);
    ps += __shfl_xor(ps, 16);
    ps += __shfl_xor(ps, 32);
    const float s = ps * scale;
    const float mnew = fmaxf(m, s);
    const float al = expf(m - mnew);   // first iter: expf(-inf)=0
    const float p = expf(s - mnew);
    const float* vr = vb + (size_t)k * QKVN;
    o1 = o1 * al + p * vr[lane];
    o2 = o2 * al + p * vr[lane + 64];
    l = l * al + p;
    m = mnew;
  }
  float* ob = out + (size_t)(b * S + q) * (NH * HD) + h * HD;
  ob[lane] = o1 / l;
  ob[lane + 64] = o2 / l;
}

// ---------------------------------------------------------------------------
extern "C" void kernel_launch(void* const* d_in, const int* in_sizes, int n_in,
                              void* d_out, int out_size, void* d_ws,
                              size_t ws_size, hipStream_t stream) {
  // Inputs: fp32, dict order (both verified on-device in rounds 5/6).
  const float* hidden = (const float*)d_in[0];  // (T, DM)
  const float* w_qkv = (const float*)d_in[1];   // (DM, QKVN)
  const float* cosb = (const float*)d_in[2];    // (T, HD)
  const float* sinb = (const float*)d_in[3];    // (T, HD)
  // OUTPUT IS FP32: reference returns float32, and the harness contract maps
  // non-bf16 reference outputs to float*. (The "bf16" in the test's assertion
  // label is hardcoded in the generated f-string — it fooled rounds 0-6.)
  float* out = (float*)d_out;                   // (T, NH*HD) fp32

  char* ws = (char*)d_ws;
  float* qkv = (float*)ws;  // (T, QKVN) fp32, 48 MiB

  gemm_naive<<<dim3(QKVN / 64, T / 64), 256, 0, stream>>>(hidden, w_qkv, qkv);
  rope_kernel<<<(T * (NH + NKVH) * 64) / 256, 256, 0, stream>>>(qkv, cosb,
                                                                sinb);
  // one wave per (b,h,q): B*NH*S waves = 65536; 4 waves/block -> 16384 blocks
  attn_naive<<<(B * NH * S * 64) / 256, 256, 0, stream>>>(qkv, out);
}